// Round 4
// baseline (288.400 us; speedup 1.0000x reference)
//
#include <hip/hip_runtime.h>
#include <math.h>

// Problem constants (fixed by the reference): B=16, C=9, H=W=512.
#define NCLS 9
#define NB 16
#define HW (512 * 512)          // labels per sample = 262144
#define NBLK_HIST 512           // 32 hist blocks per sample
#define BLKS_PER_SAMPLE 32
#define SCALE_BLOCKS 2048
#define N4 (NB * NCLS * HW / 4) // 9437184 float4s
#define STRIDE (SCALE_BLOCKS * 256)   // 524288 -> exactly 18 float4s/thread

// sched_group_barrier masks (LLVM SchedGroupMask)
#define SGB __builtin_amdgcn_sched_group_barrier
#define SG_VALU 0x2
#define SG_VMEM_READ 0x20
#define SG_VMEM_WRITE 0x40
#define SG_DS_READ 0x100

// ---------------------------------------------------------------------------
// Kernel 1: per-block partial histograms -> partial[512][9] (fully written,
// no zero-init, no atomics). 512 blocks x 256 threads, 32 labels/thread.
// ---------------------------------------------------------------------------
__global__ void __launch_bounds__(256) hist_kernel(const int* __restrict__ labels,
                                                   int* __restrict__ partial) {
    const int tid = blockIdx.x * 256 + threadIdx.x;
    const int4* l4 = (const int4*)labels;
    const int base = tid * 8;           // int4 index

    int4 v[8];
#pragma unroll
    for (int j = 0; j < 8; ++j) v[j] = l4[base + j];

    int cnt[NCLS];
#pragma unroll
    for (int c = 0; c < NCLS; ++c) cnt[c] = 0;
#pragma unroll
    for (int j = 0; j < 8; ++j) {
#pragma unroll
        for (int c = 0; c < NCLS; ++c) {
            cnt[c] += (v[j].x == c) + (v[j].y == c) + (v[j].z == c) + (v[j].w == c);
        }
    }

    __shared__ int lds[4][NCLS];        // 4 waves per block
    const int wave = threadIdx.x >> 6;
    const int lane = threadIdx.x & 63;
#pragma unroll
    for (int c = 0; c < NCLS; ++c) {
        int s = cnt[c];
#pragma unroll
        for (int off = 32; off > 0; off >>= 1) s += __shfl_down(s, off);
        if (lane == 0) lds[wave][c] = s;
    }
    __syncthreads();
    if (threadIdx.x < NCLS) {
        const int c = threadIdx.x;
        partial[blockIdx.x * NCLS + c] =
            lds[0][c] + lds[1][c] + lds[2][c] + lds[3][c];
    }
}

// ---------------------------------------------------------------------------
// Kernel 2 (fused): reduce partials -> weights in LDS, then stream-scale.
// Weight math matches the numpy reference (ddof=0, weight=1 where logh==0).
// Stream phase: 18 float4s/thread as 3 batches of 6, SOFTWARE-PIPELINED with
// two named register batches (va, vb) so loads are always issued BEFORE the
// stores they overlap with (counted vmcnt, never a full drain), and pinned
// with sched_group_barrier so the compiler cannot collapse the batching
// (R3 evidence: VGPR=28 proved it serialized the source-level batch).
// ---------------------------------------------------------------------------
__global__ void __launch_bounds__(256) fused_weight_scale_kernel(
        const int* __restrict__ partial,
        const float4* __restrict__ in,
        float4* __restrict__ out) {
    __shared__ float hsm[NB * NCLS];
    __shared__ float wsm[NB * NCLS];
    const int t = threadIdx.x;

    if (t < NB * NCLS) {
        const int b = t / NCLS;
        const int c = t % NCLS;
        const int* p = partial + b * (BLKS_PER_SAMPLE * NCLS) + c;
        int s = 0;
#pragma unroll
        for (int k = 0; k < BLKS_PER_SAMPLE; ++k) s += p[k * NCLS];
        hsm[t] = (float)s;
    }
    __syncthreads();

    if (t < NB * NCLS) {
        const int b = t / NCLS;
        const int c = t % NCLS;
        float h[NCLS];
        float total = 0.f;
#pragma unroll
        for (int k = 0; k < NCLS; ++k) {
            h[k] = hsm[b * NCLS + k];
            total += h[k];
        }
        float logh[NCLS];
        float cntbins = 0.f, sum = 0.f;
#pragma unroll
        for (int k = 0; k < NCLS; ++k) {
            float p = h[k] / total;
            float lg = (h[k] > 0.f) ? -logf(p) : 0.f;
            logh[k] = lg;
            if (h[k] > 0.f) { cntbins += 1.f; sum += lg; }
        }
        const float mean = sum / cntbins;
        float var = 0.f;
#pragma unroll
        for (int k = 0; k < NCLS; ++k) {
            if (h[k] > 0.f) {
                float d = logh[k] - mean;
                var += d * d;
            }
        }
        var /= cntbins;
        const float stdv = sqrtf(var);
        const float lc = logh[c];
        wsm[t] = (lc != 0.f) ? (lc - mean) / stdv * 0.1f + 1.0f : 1.0f;
    }
    __syncthreads();

    // ---- stream phase: straight-line, software-pipelined ----
    const int tid = blockIdx.x * 256 + t;     // 0 .. STRIDE-1

    // LOAD6: 6 independent global loads, pinned as a VMEM_READ group.
#define LOAD6(V, B0)                                                     \
    {                                                                    \
        _Pragma("unroll")                                                \
        for (int j = 0; j < 6; ++j)                                      \
            V[j] = in[tid + (B0) * 6 * STRIDE + j * STRIDE];             \
        SGB(SG_VMEM_READ, 6, 0);                                         \
    }

    // SCALE_STORE6: 6 LDS weight reads, 24 mults, 6 global stores (pinned).
#define SCALE_STORE6(V, B0)                                              \
    {                                                                    \
        _Pragma("unroll")                                                \
        for (int j = 0; j < 6; ++j) {                                    \
            const int i = tid + (B0) * 6 * STRIDE + j * STRIDE;          \
            const float w = wsm[i >> 16];                                \
            V[j].x *= w; V[j].y *= w; V[j].z *= w; V[j].w *= w;          \
            out[i] = V[j];                                               \
        }                                                                \
        SGB(SG_DS_READ, 6, 0);                                           \
        SGB(SG_VALU, 24, 0);                                             \
        SGB(SG_VMEM_WRITE, 6, 0);                                        \
    }

    float4 va[6], vb[6];
    LOAD6(va, 0)        // batch0 in flight
    LOAD6(vb, 1)        // batch1 in flight (12 loads outstanding)
    SCALE_STORE6(va, 0) // consume batch0 (wait = counted, loads oldest)
    LOAD6(va, 2)        // batch2 in flight over batch1's stores
    SCALE_STORE6(vb, 1)
    SCALE_STORE6(va, 2)
#undef LOAD6
#undef SCALE_STORE6
}

extern "C" void kernel_launch(void* const* d_in, const int* in_sizes, int n_in,
                              void* d_out, int out_size, void* d_ws, size_t ws_size,
                              hipStream_t stream) {
    const float* preds = (const float*)d_in[0];   // [16,9,512,512] f32
    const int* labels = (const int*)d_in[1];      // [16,512,512] i32
    float* out = (float*)d_out;

    // Workspace: partial[512][9] ints (fully overwritten each call -> no init)
    int* partial = (int*)d_ws;

    hist_kernel<<<NBLK_HIST, 256, 0, stream>>>(labels, partial);

    fused_weight_scale_kernel<<<SCALE_BLOCKS, 256, 0, stream>>>(
        partial, (const float4*)preds, (float4*)out);
}

// Round 5
// 269.000 us; speedup vs baseline: 1.0721x; 1.0721x over previous
//
#include <hip/hip_runtime.h>
#include <math.h>

// Problem constants (fixed by the reference): B=16, C=9, H=W=512.
#define NCLS 9
#define NB 16
#define HW (512 * 512)          // labels per sample = 262144
#define NBLK_HIST 512           // 32 hist blocks per sample
#define BLKS_PER_SAMPLE 32
#define N4 (NB * NCLS * HW / 4) // 9437184 float4s
#define SCALE_BLOCKS (N4 / 256) // 36864 blocks, exactly 1 float4/thread

// ---------------------------------------------------------------------------
// Kernel 1: per-block partial histograms -> partial[512][9] (fully written,
// no zero-init, no atomics). 512 blocks x 256 threads, 32 labels/thread.
// ---------------------------------------------------------------------------
__global__ void __launch_bounds__(256) hist_kernel(const int* __restrict__ labels,
                                                   int* __restrict__ partial) {
    const int tid = blockIdx.x * 256 + threadIdx.x;
    const int4* l4 = (const int4*)labels;
    const int base = tid * 8;           // int4 index

    int4 v[8];
#pragma unroll
    for (int j = 0; j < 8; ++j) v[j] = l4[base + j];

    int cnt[NCLS];
#pragma unroll
    for (int c = 0; c < NCLS; ++c) cnt[c] = 0;
#pragma unroll
    for (int j = 0; j < 8; ++j) {
#pragma unroll
        for (int c = 0; c < NCLS; ++c) {
            cnt[c] += (v[j].x == c) + (v[j].y == c) + (v[j].z == c) + (v[j].w == c);
        }
    }

    __shared__ int lds[4][NCLS];        // 4 waves per block
    const int wave = threadIdx.x >> 6;
    const int lane = threadIdx.x & 63;
#pragma unroll
    for (int c = 0; c < NCLS; ++c) {
        int s = cnt[c];
#pragma unroll
        for (int off = 32; off > 0; off >>= 1) s += __shfl_down(s, off);
        if (lane == 0) lds[wave][c] = s;
    }
    __syncthreads();
    if (threadIdx.x < NCLS) {
        const int c = threadIdx.x;
        partial[blockIdx.x * NCLS + c] =
            lds[0][c] + lds[1][c] + lds[2][c] + lds[3][c];
    }
}

// ---------------------------------------------------------------------------
// Kernel 2: weights from partials. One block, 192 threads (144 active).
// Thread t=(b,c) reduces this sample's 32 partials per class (L2-hot) and
// redundantly computes per-sample stats. Matches the numpy reference:
//   p = h/total; logh = (h>0) ? -log(p) : 0
//   mean/std over bins with h>0 (population variance, ddof=0)
//   weight = (logh != 0) ? (logh-mean)/std*0.1 + 1.0 : 1.0
// ---------------------------------------------------------------------------
__global__ void __launch_bounds__(192) weight_kernel(const int* __restrict__ partial,
                                                     float* __restrict__ weight) {
    const int t = threadIdx.x;
    if (t >= NB * NCLS) return;
    const int b = t / NCLS;
    const int c = t % NCLS;

    float h[NCLS];
    float total = 0.f;
#pragma unroll
    for (int k = 0; k < NCLS; ++k) {
        const int* p = partial + b * (BLKS_PER_SAMPLE * NCLS) + k;
        int s = 0;
#pragma unroll
        for (int j = 0; j < BLKS_PER_SAMPLE; ++j) s += p[j * NCLS];
        h[k] = (float)s;
        total += h[k];
    }

    float logh[NCLS];
    float cntbins = 0.f, sum = 0.f;
#pragma unroll
    for (int k = 0; k < NCLS; ++k) {
        float p = h[k] / total;
        float lg = (h[k] > 0.f) ? -logf(p) : 0.f;
        logh[k] = lg;
        if (h[k] > 0.f) { cntbins += 1.f; sum += lg; }
    }
    const float mean = sum / cntbins;
    float var = 0.f;
#pragma unroll
    for (int k = 0; k < NCLS; ++k) {
        if (h[k] > 0.f) {
            float d = logh[k] - mean;
            var += d * d;
        }
    }
    var /= cntbins;
    const float stdv = sqrtf(var);

    const float lc = logh[c];
    weight[t] = (lc != 0.f) ? (lc - mean) / stdv * 0.1f + 1.0f : 1.0f;
}

// ---------------------------------------------------------------------------
// Kernel 3: out[i] = in[i] * weight[i>>16], exactly ONE float4 per thread,
// 36864 blocks x 256 threads (fill-kernel shape: blocks stream through CUs,
// no loop, no LDS, no barrier). i>>16 is wave-uniform -> scalar load.
// ---------------------------------------------------------------------------
__global__ void __launch_bounds__(256) scale_kernel(const float4* __restrict__ in,
                                                    const float* __restrict__ weight,
                                                    float4* __restrict__ out) {
    const int i = blockIdx.x * 256 + threadIdx.x;
    const float w = weight[i >> 16];    // uniform across the wave
    float4 v = in[i];
    v.x *= w; v.y *= w; v.z *= w; v.w *= w;
    out[i] = v;
}

extern "C" void kernel_launch(void* const* d_in, const int* in_sizes, int n_in,
                              void* d_out, int out_size, void* d_ws, size_t ws_size,
                              hipStream_t stream) {
    const float* preds = (const float*)d_in[0];   // [16,9,512,512] f32
    const int* labels = (const int*)d_in[1];      // [16,512,512] i32
    float* out = (float*)d_out;

    // Workspace: partial[512][9] ints | weight[144] floats (both fully
    // overwritten every call -> no zero-init needed on poisoned ws).
    int* partial = (int*)d_ws;
    float* weight = (float*)((char*)d_ws + NBLK_HIST * NCLS * sizeof(int));

    hist_kernel<<<NBLK_HIST, 256, 0, stream>>>(labels, partial);
    weight_kernel<<<1, 192, 0, stream>>>(partial, weight);
    scale_kernel<<<SCALE_BLOCKS, 256, 0, stream>>>(
        (const float4*)preds, weight, (float4*)out);
}